// Round 12
// baseline (1091.780 us; speedup 1.0000x reference)
//
#include <hip/hip_runtime.h>

#define B_ 64
#define L_ 2048
#define D_ 128
#define LP 2056   // padded rows per batch (3 left, 5 right incl. alignment)
#define PAD 3     // SAME-pad left for W=8

typedef __attribute__((ext_vector_type(8))) short short8;
typedef __attribute__((ext_vector_type(4))) float f32x4;
typedef __attribute__((ext_vector_type(4))) unsigned short us4;

static __device__ __forceinline__ float bf2f(unsigned short u) {
  return __uint_as_float(((unsigned int)u) << 16);
}
static __device__ __forceinline__ unsigned short f2bf(float f) {
  unsigned int x = __float_as_uint(f);
  unsigned int r = (x + 0x7fffu + ((x >> 16) & 1u)) >> 16;  // RNE
  return (unsigned short)r;
}

// ---------------------------------------------------------------------------
// K0 (lite): bias gather + weight transposes + tokpad PAD rows only.
// ---------------------------------------------------------------------------
__global__ __launch_bounds__(256) void k_prep(
    const int* __restrict__ code, const float* __restrict__ bias_table,
    const float* __restrict__ Wx, const float* __restrict__ c1w,
    const float* __restrict__ c2w,
    unsigned short* __restrict__ tokpad, unsigned short* __restrict__ WxT,
    unsigned short* __restrict__ c1wT, unsigned short* __restrict__ c2wT,
    float* __restrict__ biasg)
{
  int id = blockIdx.x * 256 + threadIdx.x;
  const int NB = B_ * L_;                 // biasg
  if (id < NB) { biasg[id] = bias_table[code[id]]; return; }
  id -= NB;
  const int N3 = 192 * 128;               // WxT[c][d]
  if (id < N3) { int c = id >> 7, d = id & 127; WxT[id] = f2bf(Wx[d * 192 + c]); return; }
  id -= N3;
  const int N4 = 8 * 64 * 128;            // c1wT[w][c][d]
  if (id < N4) {
    int w = id >> 13, c = (id >> 7) & 63, d = id & 127;
    c1wT[id] = f2bf(c1w[(w * 128 + d) * 64 + c]); return;
  }
  id -= N4;
  const int N5 = 8 * 64 * 64;             // c2wT[w][c][d]
  if (id < N5) {
    int w = id >> 12, c = (id >> 6) & 63, d = id & 63;
    c2wT[id] = f2bf(c2w[(w * 64 + d) * 64 + c]); return;
  }
  id -= N5;
  // tokpad padding rows: 0..2 and 2051..2055 (zeros), 16 uint4 per row
  if (id < 8192) {
    int b = id >> 7, rem = id & 127;
    int rr = rem >> 4, c8 = rem & 15;
    int row = (rr < 3) ? rr : (2051 + rr - 3);
    uint4 z = {0u, 0u, 0u, 0u};
    ((uint4*)tokpad)[(b * LP + row) * 16 + c8] = z;
  }
}

// ---------------------------------------------------------------------------
// K1: x_proj = tok @ Wx + b_gru[0] -> bf16, gate-interleaved xg. A-tile
// gathered directly from E (same f2bf bits), written to LDS + tokpad.
// ---------------------------------------------------------------------------
__global__ __launch_bounds__(256) void k_xproj(
    const int* __restrict__ code, const float* __restrict__ E,
    const unsigned short* __restrict__ WxT, const float* __restrict__ bg,
    unsigned short* __restrict__ tokpad, unsigned short* __restrict__ xg)
{
  __shared__ __align__(16) unsigned short At[128 * 136];
  __shared__ __align__(16) unsigned short Bt[192 * 136];
  __shared__ int codes[128];
  int b = blockIdx.x >> 4;
  int l0 = (blockIdx.x & 15) << 7;
  int tid = threadIdx.x;
  if (tid < 128) codes[tid] = code[b * L_ + l0 + tid];
  __syncthreads();
  for (int i = tid; i < 128 * 16; i += 256) {
    int row = i >> 4, c8 = i & 15;
    const float4* e = (const float4*)(E + (size_t)codes[row] * D_ + c8 * 8);
    float4 e0 = e[0], e1 = e[1];
    uint4 o;
    o.x = f2bf(e0.x) | ((unsigned int)f2bf(e0.y) << 16);
    o.y = f2bf(e0.z) | ((unsigned int)f2bf(e0.w) << 16);
    o.z = f2bf(e1.x) | ((unsigned int)f2bf(e1.y) << 16);
    o.w = f2bf(e1.z) | ((unsigned int)f2bf(e1.w) << 16);
    *((uint4*)&At[row * 136 + c8 * 8]) = o;
    ((uint4*)tokpad)[(b * LP + PAD + l0 + row) * 16 + c8] = o;
  }
  for (int i = tid; i < 192 * 16; i += 256) {
    int row = i >> 4, c8 = i & 15;
    uint4 v = ((const uint4*)WxT)[i];
    *((uint4*)&Bt[row * 136 + c8 * 8]) = v;
  }
  __syncthreads();
  int wave = tid >> 6, lane = tid & 63;
  int m = lane & 15, q = lane >> 4;
  f32x4 acc[2][12];
  #pragma unroll
  for (int mt = 0; mt < 2; ++mt)
    #pragma unroll
    for (int nt = 0; nt < 12; ++nt) acc[mt][nt] = (f32x4){0.f,0.f,0.f,0.f};
  #pragma unroll
  for (int ks = 0; ks < 4; ++ks) {
    int kof = ks * 32 + q * 8;
    short8 a[2], bb[12];
    #pragma unroll
    for (int mt = 0; mt < 2; ++mt)
      a[mt] = *(const short8*)&At[(wave * 32 + mt * 16 + m) * 136 + kof];
    #pragma unroll
    for (int nt = 0; nt < 12; ++nt)
      bb[nt] = *(const short8*)&Bt[(nt * 16 + m) * 136 + kof];
    #pragma unroll
    for (int mt = 0; mt < 2; ++mt)
      #pragma unroll
      for (int nt = 0; nt < 12; ++nt)
        acc[mt][nt] = __builtin_amdgcn_mfma_f32_16x16x32_bf16(a[mt], bb[nt], acc[mt][nt], 0, 0, 0);
  }
  __syncthreads();                        // all MFMA reads of Bt done
  // deposit C (+bias, bf16) transposed into Bt[c][l]  (l = 0..127)
  #pragma unroll
  for (int mt = 0; mt < 2; ++mt) {
    int lrow = wave * 32 + mt * 16 + q * 4;
    #pragma unroll
    for (int nt = 0; nt < 12; ++nt) {
      int c = nt * 16 + m;                 // C col = lane&15
      float b0 = bg[c];
      us4 val;
      val.x = f2bf(acc[mt][nt][0] + b0);
      val.y = f2bf(acc[mt][nt][1] + b0);
      val.z = f2bf(acc[mt][nt][2] + b0);
      val.w = f2bf(acc[mt][nt][3] + b0);
      *((us4*)&Bt[c * 136 + lrow]) = val;
    }
  }
  __syncthreads();
  // gate-interleaved write-out: per (j, 4-step group): read z/r/h 4-wide,
  // pack [z|r<<16, h] per step, store 2 x uint4 (32 B contiguous per lane).
  for (int i = tid; i < 64 * 32; i += 256) {
    int j = i >> 5, g = i & 31;           // steps l = 4g..4g+3
    us4 z4 = *(const us4*)&Bt[j * 136 + g * 4];
    us4 r4 = *(const us4*)&Bt[(64 + j) * 136 + g * 4];
    us4 h4 = *(const us4*)&Bt[(128 + j) * 136 + g * 4];
    uint4 o0, o1;
    o0.x = (unsigned)z4.x | ((unsigned)r4.x << 16); o0.y = (unsigned)h4.x;
    o0.z = (unsigned)z4.y | ((unsigned)r4.y << 16); o0.w = (unsigned)h4.y;
    o1.x = (unsigned)z4.z | ((unsigned)r4.z << 16); o1.y = (unsigned)h4.z;
    o1.z = (unsigned)z4.w | ((unsigned)r4.w << 16); o1.w = (unsigned)h4.w;
    size_t stp = (size_t)(b * 64 + j) * L_ + l0 + g * 4;  // step index
    ((uint4*)xg)[stp >> 1]       = o0;
    ((uint4*)xg)[(stp >> 1) + 1] = o1;
  }
}

// ---------------------------------------------------------------------------
// K2 (fused): blocks 0..63 = GRU scan; blocks 64..255 = conv1+conv2 with
// halo recompute. VERBATIM from R16 (best measured: ~904 us).
// ---------------------------------------------------------------------------
#define BARRIER() asm volatile("s_waitcnt lgkmcnt(0)\n\ts_barrier" ::: "memory")

__global__ __launch_bounds__(192)
__attribute__((amdgpu_waves_per_eu(1, 1)))
void k_fused(
    const unsigned short* __restrict__ xg, const float* __restrict__ Wh,
    const float* __restrict__ bg, float* __restrict__ h_t,
    const unsigned short* __restrict__ tokpad,
    const unsigned short* __restrict__ c1wT, const float* __restrict__ c1b,
    const unsigned short* __restrict__ c2wT, const float* __restrict__ c2b,
    unsigned short* __restrict__ c2o)
{
  __shared__ __align__(16) unsigned short pool[39744];
  int bid = blockIdx.x;
  int tid = threadIdx.x;

  if (bid < 64) {
    // ================= GRU scan (R16: 3-wave k-split, readlane h) ========
    int w = tid >> 6, j = tid & 63;
    float* xch = (float*)pool;            // 2 parities x 3 waves x 64 x f32x4
    int b = bid;
    int kb = w * 22;                      // k-rows kb..kb+21 (padded past 63)

    float wz[22], wr[22], wh[22];
    #pragma unroll
    for (int i = 0; i < 22; ++i) {
      int k = kb + i;
      bool ok = k < 64;
      wz[i] = ok ? Wh[k * 192 + j]       : 0.f;
      wr[i] = ok ? Wh[k * 192 + 64 + j]  : 0.f;
      wh[i] = ok ? Wh[k * 192 + 128 + j] : 0.f;
    }
    #pragma unroll
    for (int i = 0; i < 22; ++i)
      asm volatile("" : "+v"(wz[i]), "+v"(wr[i]), "+v"(wh[i]));

    // bias seeds: only wave 0 carries the bias (fixed-order partial sum).
    float seedz = (w == 0) ? bg[192 + j]       : 0.f;
    float seedr = (w == 0) ? bg[192 + 64 + j]  : 0.f;
    float seedh = (w == 0) ? bg[192 + 128 + j] : 0.f;
    float hreg = 0.f;

    const uint4* xp = (const uint4*)(xg + (size_t)(b * 64 + j) * L_ * 4);
    uint4 cur_ = xp[0];
    uint4 nxt_ = xp[1];

#define STEP(WZR, WH_, P) { \
    float hk[22]; \
    _Pragma("unroll") \
    for (int i = 0; i < 22; ++i) \
      hk[i] = __int_as_float(__builtin_amdgcn_readlane(__float_as_int(hreg), (kb + i) & 63)); \
    __builtin_amdgcn_sched_barrier(0); \
    float az[4] = {seedz, 0.f, 0.f, 0.f}; \
    float ar[4] = {seedr, 0.f, 0.f, 0.f}; \
    float ah[4] = {seedh, 0.f, 0.f, 0.f}; \
    _Pragma("unroll") \
    for (int i = 0; i < 22; ++i) { \
      az[i & 3] = fmaf(hk[i], wz[i], az[i & 3]); \
      ar[i & 3] = fmaf(hk[i], wr[i], ar[i & 3]); \
      ah[i & 3] = fmaf(hk[i], wh[i], ah[i & 3]); \
    } \
    float4 pv; \
    pv.x = (az[0] + az[1]) + (az[2] + az[3]); \
    pv.y = (ar[0] + ar[1]) + (ar[2] + ar[3]); \
    pv.z = (ah[0] + ah[1]) + (ah[2] + ah[3]); \
    pv.w = 0.f; \
    *((float4*)&xch[(P) * 768 + (w * 64 + j) * 4]) = pv; \
    BARRIER(); \
    float4 q0 = *((const float4*)&xch[(P) * 768 + (0 * 64 + j) * 4]); \
    float4 q1 = *((const float4*)&xch[(P) * 768 + (1 * 64 + j) * 4]); \
    float4 q2 = *((const float4*)&xch[(P) * 768 + (2 * 64 + j) * 4]); \
    float sz = (q0.x + q1.x) + q2.x; \
    float sr = (q0.y + q1.y) + q2.y; \
    float sh = (q0.z + q1.z) + q2.z; \
    float xvz = bf2f((unsigned short)((WZR) & 0xffffu)); \
    float xvr = bf2f((unsigned short)((WZR) >> 16)); \
    float xvh = bf2f((unsigned short)((WH_) & 0xffffu)); \
    float zg = 1.f / (1.f + __expf(-(xvz + sz))); \
    float rg = 1.f / (1.f + __expf(-(xvr + sr))); \
    float e2 = __expf(-2.f * (xvh + rg * sh)); \
    float hh = fmaf(2.f, __frcp_rn(1.f + e2), -1.f); \
    hreg = zg * hreg + (1.f - zg) * hh; \
  }

    #pragma nounroll
    for (int p = 0; p < L_ / 2; ++p) {
      int pn = (p < L_ / 2 - 2) ? p + 2 : (L_ / 2 - 1);
      uint4 nn = xp[pn];
      STEP(cur_.x, cur_.y, 0)
      STEP(cur_.z, cur_.w, 1)
      cur_ = nxt_; nxt_ = nn;
    }
#undef STEP
    if (w == 0) h_t[b * 64 + j] = hreg;
    return;
  }

  // ================= fused conv1+conv2 (halo recompute) =================
  unsigned short* At    = pool;           // 152 x 136 shorts = 41344 B
  unsigned short* l1buf = pool + 20672;   // 144 x 72  shorts = 20736 B
  unsigned short* Bw    = pool + 31040;   //  64 x 136 shorts = 17408 B
  int wv = tid >> 6, lane = tid & 63;
  int m = lane & 15, q = lane >> 4;

  for (int job = bid - 64; job < 1024; job += 192) {
    int b = job >> 4;
    int l0 = (job & 15) << 7;
    __syncthreads();                      // prev job fully consumed
    for (int i = tid; i < 152 * 16; i += 192) {
      int row = i >> 4, c8 = i & 15;
      int p = l0 - 3 + row;
      p = p < 0 ? 0 : (p > 2055 ? 2055 : p);
      *((uint4*)&At[row * 136 + c8 * 8]) = ((const uint4*)tokpad)[(b * LP + p) * 16 + c8];
    }
    // ---- conv1: l1 rows [l0-3, l0+140] (9 M-tiles of 16), K=128 ----
    f32x4 acc[3][4];
    #pragma unroll
    for (int mt = 0; mt < 3; ++mt)
      #pragma unroll
      for (int nt = 0; nt < 4; ++nt) acc[mt][nt] = (f32x4){0.f,0.f,0.f,0.f};
    for (int w8 = 0; w8 < 8; ++w8) {
      __syncthreads();
      for (int i = tid; i < 64 * 16; i += 192) {
        int row = i >> 4, c8 = i & 15;
        *((uint4*)&Bw[row * 136 + c8 * 8]) = ((const uint4*)c1wT)[(w8 * 64 + row) * 16 + c8];
      }
      __syncthreads();
      #pragma unroll
      for (int ks = 0; ks < 4; ++ks) {
        int kof = ks * 32 + q * 8;
        short8 a[3], bb[4];
        #pragma unroll
        for (int mt = 0; mt < 3; ++mt) {
          int tl = wv + 3 * mt;
          a[mt] = *(const short8*)&At[(tl * 16 + m + w8) * 136 + kof];
        }
        #pragma unroll
        for (int nt = 0; nt < 4; ++nt)
          bb[nt] = *(const short8*)&Bw[(nt * 16 + m) * 136 + kof];
        #pragma unroll
        for (int mt = 0; mt < 3; ++mt)
          #pragma unroll
          for (int nt = 0; nt < 4; ++nt)
            acc[mt][nt] = __builtin_amdgcn_mfma_f32_16x16x32_bf16(a[mt], bb[nt], acc[mt][nt], 0, 0, 0);
      }
    }
    #pragma unroll
    for (int mt = 0; mt < 3; ++mt) {
      int tl = wv + 3 * mt;
      #pragma unroll
      for (int nt = 0; nt < 4; ++nt) {
        int c = nt * 16 + m;
        float bs = c1b[c];
        #pragma unroll
        for (int r = 0; r < 4; ++r) {
          float v = fmaxf(acc[mt][nt][r] + bs, 0.f);
          l1buf[(tl * 16 + q * 4 + r) * 72 + c] = f2bf(v);
        }
      }
    }
    __syncthreads();
    for (int i2 = tid; i2 < 135 * 8; i2 += 192) {
      int i = i2 >> 3, c8 = i2 & 7;
      int jrow = l0 - 3 + i;
      if (jrow < 0 || jrow > 2047) {
        uint4 z4 = {0u,0u,0u,0u};
        *((uint4*)&l1buf[i * 72 + c8 * 8]) = z4;
      }
    }
    // ---- conv2: out rows [l0, l0+127] (8 M-tiles), K=64 ----
    f32x4 acc2[3][4];
    #pragma unroll
    for (int mt = 0; mt < 3; ++mt)
      #pragma unroll
      for (int nt = 0; nt < 4; ++nt) acc2[mt][nt] = (f32x4){0.f,0.f,0.f,0.f};
    for (int w8 = 0; w8 < 8; ++w8) {
      __syncthreads();
      for (int i = tid; i < 64 * 8; i += 192) {
        int row = i >> 3, c8 = i & 7;
        *((uint4*)&Bw[row * 72 + c8 * 8]) = ((const uint4*)c2wT)[(w8 * 64 + row) * 8 + c8];
      }
      __syncthreads();
      #pragma unroll
      for (int ks = 0; ks < 2; ++ks) {
        int kof = ks * 32 + q * 8;
        short8 a[3], bb[4];
        #pragma unroll
        for (int mt = 0; mt < 3; ++mt) {
          int tl = wv + 3 * mt;
          if (tl < 8)
            a[mt] = *(const short8*)&l1buf[(tl * 16 + m + w8) * 72 + kof];
        }
        #pragma unroll
        for (int nt = 0; nt < 4; ++nt)
          bb[nt] = *(const short8*)&Bw[(nt * 16 + m) * 72 + kof];
        #pragma unroll
        for (int mt = 0; mt < 3; ++mt) {
          int tl = wv + 3 * mt;
          if (tl < 8)
            #pragma unroll
            for (int nt = 0; nt < 4; ++nt)
              acc2[mt][nt] = __builtin_amdgcn_mfma_f32_16x16x32_bf16(a[mt], bb[nt], acc2[mt][nt], 0, 0, 0);
        }
      }
    }
    #pragma unroll
    for (int mt = 0; mt < 3; ++mt) {
      int tl = wv + 3 * mt;
      if (tl < 8) {
        #pragma unroll
        for (int nt = 0; nt < 4; ++nt) {
          int c = nt * 16 + m;
          float bs = c2b[c];
          #pragma unroll
          for (int r = 0; r < 4; ++r)
            c2o[(size_t)(b * L_ + l0 + tl * 16 + q * 4 + r) * 64 + c] = f2bf(acc2[mt][nt][r] + bs);
        }
      }
    }
  }
}

// ---------------------------------------------------------------------------
// K3: a_logits, one block per (batch, 64-l tile) — verbatim.
// ---------------------------------------------------------------------------
__global__ __launch_bounds__(256) void k_alpha(
    const unsigned short* __restrict__ c2o, const float* __restrict__ h_t,
    const float* __restrict__ c3w, const float* __restrict__ c3b,
    float* __restrict__ a_out)
{
  __shared__ float Lf[71 * 65];
  __shared__ float red[256];
  __shared__ float ht[64];
  __shared__ float c3[512];
  int b = blockIdx.x >> 5;
  int tile = blockIdx.x & 31;
  int tid = threadIdx.x, lane = tid & 63, wave = tid >> 6;
  if (tid < 64) ht[tid] = h_t[b * 64 + tid];
  for (int i = tid; i < 512; i += 256) c3[i] = c3w[i];
  float c3bias = c3b[0];
  __syncthreads();
  int lt = tile << 6;
  for (int i0 = wave; i0 < 71; i0 += 4) {
    int l = lt - 3 + i0;
    float v = 0.f;
    if (l >= 0 && l < L_) v = bf2f(c2o[((size_t)b * L_ + l) * 64 + lane]) * ht[lane];
    float ss = v * v;
    #pragma unroll
    for (int msk = 1; msk < 64; msk <<= 1) ss += __shfl_xor(ss, msk);
    Lf[i0 * 65 + lane] = v * rsqrtf(ss + 1e-12f);
  }
  __syncthreads();
  {
    int u = lane, part = wave;
    float p = 0.f;
    #pragma unroll
    for (int w = 0; w < 8; ++w)
      #pragma unroll
      for (int cc = 0; cc < 16; ++cc) {
        int c = part * 16 + cc;
        p += Lf[(u + w) * 65 + c] * c3[w * 64 + c];
      }
    red[tid] = p;
  }
  __syncthreads();
  if (tid < 64)
    a_out[b * L_ + lt + tid] = red[tid] + red[64 + tid] + red[128 + tid] + red[192 + tid] + c3bias;
}

// ---------------------------------------------------------------------------
// K4 (R22): n_hat partials with the alpha softmax FUSED. Each of the 8
// blocks per batch redundantly computes the softmax stats over the raw
// a_logits (same op order as old k_soft1 -> identical mx/sm/inv bits) and
// applies exp(a-mx)*inv on the fly (exp recomputation = same bits as the
// old stored alpha). Removes k_soft1 (one launch + one global round trip).
// ---------------------------------------------------------------------------
__global__ __launch_bounds__(256) void k_nhat(
    const unsigned short* __restrict__ tokpad, const float* __restrict__ alog,
    float* __restrict__ npart)
{
  __shared__ float a_lds[2048];
  __shared__ float red[256];
  __shared__ float nred[512];
  int b = blockIdx.x >> 3, c = blockIdx.x & 7;
  int tid = threadIdx.x, lane = tid & 63, wave = tid >> 6;
  for (int i = tid; i < 2048; i += 256) a_lds[i] = alog[b * L_ + i];
  __syncthreads();
  // softmax stats (verbatim k_soft1 op order)
  float mx = -1e30f;
  for (int i = tid; i < 2048; i += 256) mx = fmaxf(mx, a_lds[i]);
  #pragma unroll
  for (int msk = 1; msk < 64; msk <<= 1) mx = fmaxf(mx, __shfl_xor(mx, msk));
  if (lane == 0) red[wave] = mx;
  __syncthreads();
  mx = fmaxf(fmaxf(red[0], red[1]), fmaxf(red[2], red[3]));
  float sm = 0.f;
  for (int i = tid; i < 2048; i += 256) sm += __expf(a_lds[i] - mx);
  #pragma unroll
  for (int msk = 1; msk < 64; msk <<= 1) sm += __shfl_xor(sm, msk);
  __syncthreads();
  if (lane == 0) red[wave] = sm;
  __syncthreads();
  sm = red[0] + red[1] + red[2] + red[3];
  float inv = 1.f / sm;
  // partial n_hat over this block's 256-l chunk (alpha computed on the fly)
  int d2 = tid & 63, g = tid >> 6;
  int l0 = c << 8;
  float ax = 0.f, ay = 0.f;
  for (int i = 0; i < 64; ++i) {
    int l = l0 + g + 4 * i;
    unsigned int uu = *(const unsigned int*)&tokpad[((size_t)b * LP + PAD + l) * 128 + d2 * 2];
    float al = __expf(a_lds[l] - mx) * inv;
    ax += al * bf2f((unsigned short)(uu & 0xffffu));
    ay += al * bf2f((unsigned short)(uu >> 16));
  }
  nred[g * 128 + d2 * 2] = ax;
  nred[g * 128 + d2 * 2 + 1] = ay;
  __syncthreads();
  if (tid < 128)
    npart[((b << 3) + c) * 128 + tid] = nred[tid] + nred[128 + tid] + nred[256 + tid] + nred[384 + tid];
}

// ---------------------------------------------------------------------------
// K5 (R22): combine npart -> nhat, compute ALL 2048 logits of one batch
// (old pass-4 loop verbatim), then the final softmax in-block (old pass-5
// verbatim) -> out. Removes k_soft2 (one launch + the l_all round trip).
// ---------------------------------------------------------------------------
__global__ __launch_bounds__(256) void k_logits(
    const unsigned short* __restrict__ tokpad, const float* __restrict__ npart,
    const float* __restrict__ biasg, float* __restrict__ out)
{
  __shared__ float nhat[128];
  __shared__ float l_lds[2048];
  __shared__ float red[256];
  int b = blockIdx.x;
  int tid = threadIdx.x, lane = tid & 63, wave = tid >> 6;
  if (tid < 128) {
    const float* p = npart + (b << 3) * 128 + tid;
    nhat[tid] = ((p[0] + p[128]) + (p[256] + p[384]))
              + ((p[512] + p[640]) + (p[768] + p[896]));
  }
  __syncthreads();
  // ---- logits = tok . n_hat + bias (pass-4 verbatim) ----
  for (int li = 0; li < 8; ++li) {
    int l = li * 256 + tid;
    const uint4* rowp = (const uint4*)&tokpad[((size_t)b * LP + PAD + l) * 128];
    float s = 0.f;
    #pragma unroll
    for (int jj = 0; jj < 16; ++jj) {
      uint4 uu = rowp[jj];
      s += bf2f((unsigned short)(uu.x & 0xffffu)) * nhat[jj*8+0]
         + bf2f((unsigned short)(uu.x >> 16))     * nhat[jj*8+1]
         + bf2f((unsigned short)(uu.y & 0xffffu)) * nhat[jj*8+2]
         + bf2f((unsigned short)(uu.y >> 16))     * nhat[jj*8+3]
         + bf2f((unsigned short)(uu.z & 0xffffu)) * nhat[jj*8+4]
         + bf2f((unsigned short)(uu.z >> 16))     * nhat[jj*8+5]
         + bf2f((unsigned short)(uu.w & 0xffffu)) * nhat[jj*8+6]
         + bf2f((unsigned short)(uu.w >> 16))     * nhat[jj*8+7];
    }
    l_lds[l] = s + biasg[b * L_ + l];
  }
  __syncthreads();
  // ---- final softmax (pass-5 verbatim) -> out ----
  float mx = -1e30f;
  for (int i = tid; i < 2048; i += 256) mx = fmaxf(mx, l_lds[i]);
  #pragma unroll
  for (int msk = 1; msk < 64; msk <<= 1) mx = fmaxf(mx, __shfl_xor(mx, msk));
  __syncthreads();
  if (lane == 0) red[wave] = mx;
  __syncthreads();
  mx = fmaxf(fmaxf(red[0], red[1]), fmaxf(red[2], red[3]));
  float sm = 0.f;
  for (int i = tid; i < 2048; i += 256) sm += __expf(l_lds[i] - mx);
  #pragma unroll
  for (int msk = 1; msk < 64; msk <<= 1) sm += __shfl_xor(sm, msk);
  __syncthreads();
  if (lane == 0) red[wave] = sm;
  __syncthreads();
  sm = red[0] + red[1] + red[2] + red[3];
  float inv = 1.f / sm;
  for (int i = tid; i < 2048; i += 256) out[b * L_ + i] = __expf(l_lds[i] - mx) * inv;
}

// ---------------------------------------------------------------------------
extern "C" void kernel_launch(void* const* d_in, const int* in_sizes, int n_in,
                              void* d_out, int out_size, void* d_ws, size_t ws_size,
                              hipStream_t stream) {
  const int*   code = (const int*)d_in[0];
  const float* E    = (const float*)d_in[1];
  const float* bt   = (const float*)d_in[2];
  const float* Wx   = (const float*)d_in[3];
  const float* Wh   = (const float*)d_in[4];
  const float* bg   = (const float*)d_in[5];
  const float* c1w  = (const float*)d_in[6];
  const float* c1b  = (const float*)d_in[7];
  const float* c2w  = (const float*)d_in[8];
  const float* c2b  = (const float*)d_in[9];
  const float* c3w  = (const float*)d_in[10];
  const float* c3b  = (const float*)d_in[11];
  char* ws = (char*)d_ws;
  unsigned short* tokpad = (unsigned short*)(ws);               // 33,685,504 B
  unsigned short* xg     = (unsigned short*)(ws + 33685504);    // 67,108,864 B
  unsigned short* c2o    = (unsigned short*)(ws + 100794368);   // 16,777,216 B
  unsigned short* WxT    = (unsigned short*)(ws + 117571584);   //     49,152 B
  unsigned short* c1wT   = (unsigned short*)(ws + 117620736);   //    131,072 B
  unsigned short* c2wT   = (unsigned short*)(ws + 117751808);   //     65,536 B
  float*          htp    = (float*)(ws + 117817344);            //     16,384 B
  float*          biasg  = (float*)(ws + 117833728);            //    524,288 B
  // tail buffers reuse xg space (dead after k_fused):
  float*          alog   = (float*)(ws + 33685504);             //    524,288 B
  float*          npart  = (float*)(ws + 33685504 + 1048576);   //    262,144 B
  // total ws use: 118,358,016 B

  k_prep  <<<1024, 256, 0, stream>>>(code, bt, Wx, c1w, c2w, tokpad, WxT, c1wT, c2wT, biasg);
  k_xproj <<<1024, 256, 0, stream>>>(code, E, WxT, bg, tokpad, xg);
  k_fused <<<256, 192, 0, stream>>>(xg, Wh, bg, htp, tokpad, c1wT, c1b, c2wT, c2b, c2o);
  k_alpha <<<2048, 256, 0, stream>>>(c2o, htp, c3w, c3b, alog);
  k_nhat  <<<512, 256, 0, stream>>>(tokpad, alog, npart);
  k_logits<<<64, 256, 0, stream>>>(tokpad, npart, biasg, (float*)d_out);
}

// Round 13
// 1078.674 us; speedup vs baseline: 1.0121x; 1.0121x over previous
//
#include <hip/hip_runtime.h>

#define B_ 64
#define L_ 2048
#define D_ 128
#define LP 2056   // padded rows per batch (3 left, 5 right incl. alignment)
#define PAD 3     // SAME-pad left for W=8

typedef __attribute__((ext_vector_type(8))) short short8;
typedef __attribute__((ext_vector_type(4))) float f32x4;
typedef __attribute__((ext_vector_type(4))) unsigned short us4;

static __device__ __forceinline__ float bf2f(unsigned short u) {
  return __uint_as_float(((unsigned int)u) << 16);
}
static __device__ __forceinline__ unsigned short f2bf(float f) {
  unsigned int x = __float_as_uint(f);
  unsigned int r = (x + 0x7fffu + ((x >> 16) & 1u)) >> 16;  // RNE
  return (unsigned short)r;
}

// ---------------------------------------------------------------------------
// K0 (lite): bias gather + weight transposes + tokpad PAD rows only.
// ---------------------------------------------------------------------------
__global__ __launch_bounds__(256) void k_prep(
    const int* __restrict__ code, const float* __restrict__ bias_table,
    const float* __restrict__ Wx, const float* __restrict__ c1w,
    const float* __restrict__ c2w,
    unsigned short* __restrict__ tokpad, unsigned short* __restrict__ WxT,
    unsigned short* __restrict__ c1wT, unsigned short* __restrict__ c2wT,
    float* __restrict__ biasg)
{
  int id = blockIdx.x * 256 + threadIdx.x;
  const int NB = B_ * L_;                 // biasg
  if (id < NB) { biasg[id] = bias_table[code[id]]; return; }
  id -= NB;
  const int N3 = 192 * 128;               // WxT[c][d]
  if (id < N3) { int c = id >> 7, d = id & 127; WxT[id] = f2bf(Wx[d * 192 + c]); return; }
  id -= N3;
  const int N4 = 8 * 64 * 128;            // c1wT[w][c][d]
  if (id < N4) {
    int w = id >> 13, c = (id >> 7) & 63, d = id & 127;
    c1wT[id] = f2bf(c1w[(w * 128 + d) * 64 + c]); return;
  }
  id -= N4;
  const int N5 = 8 * 64 * 64;             // c2wT[w][c][d]
  if (id < N5) {
    int w = id >> 12, c = (id >> 6) & 63, d = id & 63;
    c2wT[id] = f2bf(c2w[(w * 64 + d) * 64 + c]); return;
  }
  id -= N5;
  // tokpad padding rows: 0..2 and 2051..2055 (zeros), 16 uint4 per row
  if (id < 8192) {
    int b = id >> 7, rem = id & 127;
    int rr = rem >> 4, c8 = rem & 15;
    int row = (rr < 3) ? rr : (2051 + rr - 3);
    uint4 z = {0u, 0u, 0u, 0u};
    ((uint4*)tokpad)[(b * LP + row) * 16 + c8] = z;
  }
}

// ---------------------------------------------------------------------------
// K1: x_proj = tok @ Wx + b_gru[0] -> bf16, gate-interleaved xg. A-tile
// gathered directly from E (same f2bf bits), written to LDS + tokpad.
// ---------------------------------------------------------------------------
__global__ __launch_bounds__(256) void k_xproj(
    const int* __restrict__ code, const float* __restrict__ E,
    const unsigned short* __restrict__ WxT, const float* __restrict__ bg,
    unsigned short* __restrict__ tokpad, unsigned short* __restrict__ xg)
{
  __shared__ __align__(16) unsigned short At[128 * 136];
  __shared__ __align__(16) unsigned short Bt[192 * 136];
  __shared__ int codes[128];
  int b = blockIdx.x >> 4;
  int l0 = (blockIdx.x & 15) << 7;
  int tid = threadIdx.x;
  if (tid < 128) codes[tid] = code[b * L_ + l0 + tid];
  __syncthreads();
  for (int i = tid; i < 128 * 16; i += 256) {
    int row = i >> 4, c8 = i & 15;
    const float4* e = (const float4*)(E + (size_t)codes[row] * D_ + c8 * 8);
    float4 e0 = e[0], e1 = e[1];
    uint4 o;
    o.x = f2bf(e0.x) | ((unsigned int)f2bf(e0.y) << 16);
    o.y = f2bf(e0.z) | ((unsigned int)f2bf(e0.w) << 16);
    o.z = f2bf(e1.x) | ((unsigned int)f2bf(e1.y) << 16);
    o.w = f2bf(e1.z) | ((unsigned int)f2bf(e1.w) << 16);
    *((uint4*)&At[row * 136 + c8 * 8]) = o;
    ((uint4*)tokpad)[(b * LP + PAD + l0 + row) * 16 + c8] = o;
  }
  for (int i = tid; i < 192 * 16; i += 256) {
    int row = i >> 4, c8 = i & 15;
    uint4 v = ((const uint4*)WxT)[i];
    *((uint4*)&Bt[row * 136 + c8 * 8]) = v;
  }
  __syncthreads();
  int wave = tid >> 6, lane = tid & 63;
  int m = lane & 15, q = lane >> 4;
  f32x4 acc[2][12];
  #pragma unroll
  for (int mt = 0; mt < 2; ++mt)
    #pragma unroll
    for (int nt = 0; nt < 12; ++nt) acc[mt][nt] = (f32x4){0.f,0.f,0.f,0.f};
  #pragma unroll
  for (int ks = 0; ks < 4; ++ks) {
    int kof = ks * 32 + q * 8;
    short8 a[2], bb[12];
    #pragma unroll
    for (int mt = 0; mt < 2; ++mt)
      a[mt] = *(const short8*)&At[(wave * 32 + mt * 16 + m) * 136 + kof];
    #pragma unroll
    for (int nt = 0; nt < 12; ++nt)
      bb[nt] = *(const short8*)&Bt[(nt * 16 + m) * 136 + kof];
    #pragma unroll
    for (int mt = 0; mt < 2; ++mt)
      #pragma unroll
      for (int nt = 0; nt < 12; ++nt)
        acc[mt][nt] = __builtin_amdgcn_mfma_f32_16x16x32_bf16(a[mt], bb[nt], acc[mt][nt], 0, 0, 0);
  }
  __syncthreads();                        // all MFMA reads of Bt done
  // deposit C (+bias, bf16) transposed into Bt[c][l]  (l = 0..127)
  #pragma unroll
  for (int mt = 0; mt < 2; ++mt) {
    int lrow = wave * 32 + mt * 16 + q * 4;
    #pragma unroll
    for (int nt = 0; nt < 12; ++nt) {
      int c = nt * 16 + m;                 // C col = lane&15
      float b0 = bg[c];
      us4 val;
      val.x = f2bf(acc[mt][nt][0] + b0);
      val.y = f2bf(acc[mt][nt][1] + b0);
      val.z = f2bf(acc[mt][nt][2] + b0);
      val.w = f2bf(acc[mt][nt][3] + b0);
      *((us4*)&Bt[c * 136 + lrow]) = val;
    }
  }
  __syncthreads();
  // gate-interleaved write-out: per (j, 4-step group): read z/r/h 4-wide,
  // pack [z|r<<16, h] per step, store 2 x uint4 (32 B contiguous per lane).
  for (int i = tid; i < 64 * 32; i += 256) {
    int j = i >> 5, g = i & 31;           // steps l = 4g..4g+3
    us4 z4 = *(const us4*)&Bt[j * 136 + g * 4];
    us4 r4 = *(const us4*)&Bt[(64 + j) * 136 + g * 4];
    us4 h4 = *(const us4*)&Bt[(128 + j) * 136 + g * 4];
    uint4 o0, o1;
    o0.x = (unsigned)z4.x | ((unsigned)r4.x << 16); o0.y = (unsigned)h4.x;
    o0.z = (unsigned)z4.y | ((unsigned)r4.y << 16); o0.w = (unsigned)h4.y;
    o1.x = (unsigned)z4.z | ((unsigned)r4.z << 16); o1.y = (unsigned)h4.z;
    o1.z = (unsigned)z4.w | ((unsigned)r4.w << 16); o1.w = (unsigned)h4.w;
    size_t stp = (size_t)(b * 64 + j) * L_ + l0 + g * 4;  // step index
    ((uint4*)xg)[stp >> 1]       = o0;
    ((uint4*)xg)[(stp >> 1) + 1] = o1;
  }
}

// ---------------------------------------------------------------------------
// K2 (fused): blocks 0..63 = GRU scan; blocks 64..255 = conv1+conv2 with
// halo recompute. VERBATIM from R16 (best measured: ~904 us).
// ---------------------------------------------------------------------------
#define BARRIER() asm volatile("s_waitcnt lgkmcnt(0)\n\ts_barrier" ::: "memory")

__global__ __launch_bounds__(192)
__attribute__((amdgpu_waves_per_eu(1, 1)))
void k_fused(
    const unsigned short* __restrict__ xg, const float* __restrict__ Wh,
    const float* __restrict__ bg, float* __restrict__ h_t,
    const unsigned short* __restrict__ tokpad,
    const unsigned short* __restrict__ c1wT, const float* __restrict__ c1b,
    const unsigned short* __restrict__ c2wT, const float* __restrict__ c2b,
    unsigned short* __restrict__ c2o)
{
  __shared__ __align__(16) unsigned short pool[39744];
  int bid = blockIdx.x;
  int tid = threadIdx.x;

  if (bid < 64) {
    // ================= GRU scan (R16: 3-wave k-split, readlane h) ========
    int w = tid >> 6, j = tid & 63;
    float* xch = (float*)pool;            // 2 parities x 3 waves x 64 x f32x4
    int b = bid;
    int kb = w * 22;                      // k-rows kb..kb+21 (padded past 63)

    float wz[22], wr[22], wh[22];
    #pragma unroll
    for (int i = 0; i < 22; ++i) {
      int k = kb + i;
      bool ok = k < 64;
      wz[i] = ok ? Wh[k * 192 + j]       : 0.f;
      wr[i] = ok ? Wh[k * 192 + 64 + j]  : 0.f;
      wh[i] = ok ? Wh[k * 192 + 128 + j] : 0.f;
    }
    #pragma unroll
    for (int i = 0; i < 22; ++i)
      asm volatile("" : "+v"(wz[i]), "+v"(wr[i]), "+v"(wh[i]));

    // bias seeds: only wave 0 carries the bias (fixed-order partial sum).
    float seedz = (w == 0) ? bg[192 + j]       : 0.f;
    float seedr = (w == 0) ? bg[192 + 64 + j]  : 0.f;
    float seedh = (w == 0) ? bg[192 + 128 + j] : 0.f;
    float hreg = 0.f;

    const uint4* xp = (const uint4*)(xg + (size_t)(b * 64 + j) * L_ * 4);
    uint4 cur_ = xp[0];
    uint4 nxt_ = xp[1];

#define STEP(WZR, WH_, P) { \
    float hk[22]; \
    _Pragma("unroll") \
    for (int i = 0; i < 22; ++i) \
      hk[i] = __int_as_float(__builtin_amdgcn_readlane(__float_as_int(hreg), (kb + i) & 63)); \
    __builtin_amdgcn_sched_barrier(0); \
    float az[4] = {seedz, 0.f, 0.f, 0.f}; \
    float ar[4] = {seedr, 0.f, 0.f, 0.f}; \
    float ah[4] = {seedh, 0.f, 0.f, 0.f}; \
    _Pragma("unroll") \
    for (int i = 0; i < 22; ++i) { \
      az[i & 3] = fmaf(hk[i], wz[i], az[i & 3]); \
      ar[i & 3] = fmaf(hk[i], wr[i], ar[i & 3]); \
      ah[i & 3] = fmaf(hk[i], wh[i], ah[i & 3]); \
    } \
    float4 pv; \
    pv.x = (az[0] + az[1]) + (az[2] + az[3]); \
    pv.y = (ar[0] + ar[1]) + (ar[2] + ar[3]); \
    pv.z = (ah[0] + ah[1]) + (ah[2] + ah[3]); \
    pv.w = 0.f; \
    *((float4*)&xch[(P) * 768 + (w * 64 + j) * 4]) = pv; \
    BARRIER(); \
    float4 q0 = *((const float4*)&xch[(P) * 768 + (0 * 64 + j) * 4]); \
    float4 q1 = *((const float4*)&xch[(P) * 768 + (1 * 64 + j) * 4]); \
    float4 q2 = *((const float4*)&xch[(P) * 768 + (2 * 64 + j) * 4]); \
    float sz = (q0.x + q1.x) + q2.x; \
    float sr = (q0.y + q1.y) + q2.y; \
    float sh = (q0.z + q1.z) + q2.z; \
    float xvz = bf2f((unsigned short)((WZR) & 0xffffu)); \
    float xvr = bf2f((unsigned short)((WZR) >> 16)); \
    float xvh = bf2f((unsigned short)((WH_) & 0xffffu)); \
    float zg = 1.f / (1.f + __expf(-(xvz + sz))); \
    float rg = 1.f / (1.f + __expf(-(xvr + sr))); \
    float e2 = __expf(-2.f * (xvh + rg * sh)); \
    float hh = fmaf(2.f, __frcp_rn(1.f + e2), -1.f); \
    hreg = zg * hreg + (1.f - zg) * hh; \
  }

    #pragma nounroll
    for (int p = 0; p < L_ / 2; ++p) {
      int pn = (p < L_ / 2 - 2) ? p + 2 : (L_ / 2 - 1);
      uint4 nn = xp[pn];
      STEP(cur_.x, cur_.y, 0)
      STEP(cur_.z, cur_.w, 1)
      cur_ = nxt_; nxt_ = nn;
    }
#undef STEP
    if (w == 0) h_t[b * 64 + j] = hreg;
    return;
  }

  // ================= fused conv1+conv2 (halo recompute) =================
  unsigned short* At    = pool;           // 152 x 136 shorts = 41344 B
  unsigned short* l1buf = pool + 20672;   // 144 x 72  shorts = 20736 B
  unsigned short* Bw    = pool + 31040;   //  64 x 136 shorts = 17408 B
  int wv = tid >> 6, lane = tid & 63;
  int m = lane & 15, q = lane >> 4;

  for (int job = bid - 64; job < 1024; job += 192) {
    int b = job >> 4;
    int l0 = (job & 15) << 7;
    __syncthreads();                      // prev job fully consumed
    for (int i = tid; i < 152 * 16; i += 192) {
      int row = i >> 4, c8 = i & 15;
      int p = l0 - 3 + row;
      p = p < 0 ? 0 : (p > 2055 ? 2055 : p);
      *((uint4*)&At[row * 136 + c8 * 8]) = ((const uint4*)tokpad)[(b * LP + p) * 16 + c8];
    }
    // ---- conv1: l1 rows [l0-3, l0+140] (9 M-tiles of 16), K=128 ----
    f32x4 acc[3][4];
    #pragma unroll
    for (int mt = 0; mt < 3; ++mt)
      #pragma unroll
      for (int nt = 0; nt < 4; ++nt) acc[mt][nt] = (f32x4){0.f,0.f,0.f,0.f};
    for (int w8 = 0; w8 < 8; ++w8) {
      __syncthreads();
      for (int i = tid; i < 64 * 16; i += 192) {
        int row = i >> 4, c8 = i & 15;
        *((uint4*)&Bw[row * 136 + c8 * 8]) = ((const uint4*)c1wT)[(w8 * 64 + row) * 16 + c8];
      }
      __syncthreads();
      #pragma unroll
      for (int ks = 0; ks < 4; ++ks) {
        int kof = ks * 32 + q * 8;
        short8 a[3], bb[4];
        #pragma unroll
        for (int mt = 0; mt < 3; ++mt) {
          int tl = wv + 3 * mt;
          a[mt] = *(const short8*)&At[(tl * 16 + m + w8) * 136 + kof];
        }
        #pragma unroll
        for (int nt = 0; nt < 4; ++nt)
          bb[nt] = *(const short8*)&Bw[(nt * 16 + m) * 136 + kof];
        #pragma unroll
        for (int mt = 0; mt < 3; ++mt)
          #pragma unroll
          for (int nt = 0; nt < 4; ++nt)
            acc[mt][nt] = __builtin_amdgcn_mfma_f32_16x16x32_bf16(a[mt], bb[nt], acc[mt][nt], 0, 0, 0);
      }
    }
    #pragma unroll
    for (int mt = 0; mt < 3; ++mt) {
      int tl = wv + 3 * mt;
      #pragma unroll
      for (int nt = 0; nt < 4; ++nt) {
        int c = nt * 16 + m;
        float bs = c1b[c];
        #pragma unroll
        for (int r = 0; r < 4; ++r) {
          float v = fmaxf(acc[mt][nt][r] + bs, 0.f);
          l1buf[(tl * 16 + q * 4 + r) * 72 + c] = f2bf(v);
        }
      }
    }
    __syncthreads();
    for (int i2 = tid; i2 < 135 * 8; i2 += 192) {
      int i = i2 >> 3, c8 = i2 & 7;
      int jrow = l0 - 3 + i;
      if (jrow < 0 || jrow > 2047) {
        uint4 z4 = {0u,0u,0u,0u};
        *((uint4*)&l1buf[i * 72 + c8 * 8]) = z4;
      }
    }
    // ---- conv2: out rows [l0, l0+127] (8 M-tiles), K=64 ----
    f32x4 acc2[3][4];
    #pragma unroll
    for (int mt = 0; mt < 3; ++mt)
      #pragma unroll
      for (int nt = 0; nt < 4; ++nt) acc2[mt][nt] = (f32x4){0.f,0.f,0.f,0.f};
    for (int w8 = 0; w8 < 8; ++w8) {
      __syncthreads();
      for (int i = tid; i < 64 * 8; i += 192) {
        int row = i >> 3, c8 = i & 7;
        *((uint4*)&Bw[row * 72 + c8 * 8]) = ((const uint4*)c2wT)[(w8 * 64 + row) * 8 + c8];
      }
      __syncthreads();
      #pragma unroll
      for (int ks = 0; ks < 2; ++ks) {
        int kof = ks * 32 + q * 8;
        short8 a[3], bb[4];
        #pragma unroll
        for (int mt = 0; mt < 3; ++mt) {
          int tl = wv + 3 * mt;
          if (tl < 8)
            a[mt] = *(const short8*)&l1buf[(tl * 16 + m + w8) * 72 + kof];
        }
        #pragma unroll
        for (int nt = 0; nt < 4; ++nt)
          bb[nt] = *(const short8*)&Bw[(nt * 16 + m) * 72 + kof];
        #pragma unroll
        for (int mt = 0; mt < 3; ++mt) {
          int tl = wv + 3 * mt;
          if (tl < 8)
            #pragma unroll
            for (int nt = 0; nt < 4; ++nt)
              acc2[mt][nt] = __builtin_amdgcn_mfma_f32_16x16x32_bf16(a[mt], bb[nt], acc2[mt][nt], 0, 0, 0);
        }
      }
    }
    #pragma unroll
    for (int mt = 0; mt < 3; ++mt) {
      int tl = wv + 3 * mt;
      if (tl < 8) {
        #pragma unroll
        for (int nt = 0; nt < 4; ++nt) {
          int c = nt * 16 + m;
          float bs = c2b[c];
          #pragma unroll
          for (int r = 0; r < 4; ++r)
            c2o[(size_t)(b * L_ + l0 + tl * 16 + q * 4 + r) * 64 + c] = f2bf(acc2[mt][nt][r] + bs);
        }
      }
    }
  }
}

// ---------------------------------------------------------------------------
// K3: a_logits, one block per (batch, 64-l tile) — verbatim.
// ---------------------------------------------------------------------------
__global__ __launch_bounds__(256) void k_alpha(
    const unsigned short* __restrict__ c2o, const float* __restrict__ h_t,
    const float* __restrict__ c3w, const float* __restrict__ c3b,
    float* __restrict__ a_out)
{
  __shared__ float Lf[71 * 65];
  __shared__ float red[256];
  __shared__ float ht[64];
  __shared__ float c3[512];
  int b = blockIdx.x >> 5;
  int tile = blockIdx.x & 31;
  int tid = threadIdx.x, lane = tid & 63, wave = tid >> 6;
  if (tid < 64) ht[tid] = h_t[b * 64 + tid];
  for (int i = tid; i < 512; i += 256) c3[i] = c3w[i];
  float c3bias = c3b[0];
  __syncthreads();
  int lt = tile << 6;
  for (int i0 = wave; i0 < 71; i0 += 4) {
    int l = lt - 3 + i0;
    float v = 0.f;
    if (l >= 0 && l < L_) v = bf2f(c2o[((size_t)b * L_ + l) * 64 + lane]) * ht[lane];
    float ss = v * v;
    #pragma unroll
    for (int msk = 1; msk < 64; msk <<= 1) ss += __shfl_xor(ss, msk);
    Lf[i0 * 65 + lane] = v * rsqrtf(ss + 1e-12f);
  }
  __syncthreads();
  {
    int u = lane, part = wave;
    float p = 0.f;
    #pragma unroll
    for (int w = 0; w < 8; ++w)
      #pragma unroll
      for (int cc = 0; cc < 16; ++cc) {
        int c = part * 16 + cc;
        p += Lf[(u + w) * 65 + c] * c3[w * 64 + c];
      }
    red[tid] = p;
  }
  __syncthreads();
  if (tid < 64)
    a_out[b * L_ + lt + tid] = red[tid] + red[64 + tid] + red[128 + tid] + red[192 + tid] + c3bias;
}

// ---------------------------------------------------------------------------
// K4: alpha softmax over 2048, per batch, in-place (verbatim R20).
// ---------------------------------------------------------------------------
__global__ __launch_bounds__(256) void k_soft1(float* __restrict__ a)
{
  __shared__ float a_lds[2048];
  __shared__ float red[256];
  int b = blockIdx.x, tid = threadIdx.x, lane = tid & 63, wave = tid >> 6;
  for (int i = tid; i < 2048; i += 256) a_lds[i] = a[b * L_ + i];
  __syncthreads();
  float mx = -1e30f;
  for (int i = tid; i < 2048; i += 256) mx = fmaxf(mx, a_lds[i]);
  #pragma unroll
  for (int msk = 1; msk < 64; msk <<= 1) mx = fmaxf(mx, __shfl_xor(mx, msk));
  if (lane == 0) red[wave] = mx;
  __syncthreads();
  mx = fmaxf(fmaxf(red[0], red[1]), fmaxf(red[2], red[3]));
  float sm = 0.f;
  for (int i = tid; i < 2048; i += 256) sm += __expf(a_lds[i] - mx);
  #pragma unroll
  for (int msk = 1; msk < 64; msk <<= 1) sm += __shfl_xor(sm, msk);
  __syncthreads();
  if (lane == 0) red[wave] = sm;
  __syncthreads();
  sm = red[0] + red[1] + red[2] + red[3];
  float inv = 1.f / sm;
  for (int i = tid; i < 2048; i += 256) a[b * L_ + i] = __expf(a_lds[i] - mx) * inv;
}

// ---------------------------------------------------------------------------
// K5: partial n_hat per (b, 256-l chunk) — verbatim R20.
// ---------------------------------------------------------------------------
__global__ __launch_bounds__(256) void k_nhat(
    const unsigned short* __restrict__ tokpad, const float* __restrict__ alpha,
    float* __restrict__ npart)
{
  __shared__ float nred[512];
  int b = blockIdx.x >> 3, c = blockIdx.x & 7;
  int tid = threadIdx.x;
  int d2 = tid & 63, g = tid >> 6;
  int l0 = c << 8;
  float ax = 0.f, ay = 0.f;
  for (int i = 0; i < 64; ++i) {
    int l = l0 + g + 4 * i;
    unsigned int uu = *(const unsigned int*)&tokpad[((size_t)b * LP + PAD + l) * 128 + d2 * 2];
    float al = alpha[b * L_ + l];
    ax += al * bf2f((unsigned short)(uu & 0xffffu));
    ay += al * bf2f((unsigned short)(uu >> 16));
  }
  nred[g * 128 + d2 * 2] = ax;
  nred[g * 128 + d2 * 2 + 1] = ay;
  __syncthreads();
  if (tid < 128)
    npart[((b << 3) + c) * 128 + tid] = nred[tid] + nred[128 + tid] + nred[256 + tid] + nred[384 + tid];
}

// ---------------------------------------------------------------------------
// K6: combine npart -> nhat (LDS), then 256 logits per block — verbatim R20.
// ---------------------------------------------------------------------------
__global__ __launch_bounds__(256) void k_logits(
    const unsigned short* __restrict__ tokpad, const float* __restrict__ npart,
    const float* __restrict__ biasg, float* __restrict__ l_all)
{
  __shared__ float nhat[128];
  int b = blockIdx.x >> 3, c = blockIdx.x & 7;
  int tid = threadIdx.x;
  if (tid < 128) {
    const float* p = npart + (b << 3) * 128 + tid;
    nhat[tid] = ((p[0] + p[128]) + (p[256] + p[384]))
              + ((p[512] + p[640]) + (p[768] + p[896]));
  }
  __syncthreads();
  int l = (c << 8) + tid;
  const uint4* rowp = (const uint4*)&tokpad[((size_t)b * LP + PAD + l) * 128];
  float s = 0.f;
  #pragma unroll
  for (int jj = 0; jj < 16; ++jj) {
    uint4 uu = rowp[jj];
    s += bf2f((unsigned short)(uu.x & 0xffffu)) * nhat[jj*8+0]
       + bf2f((unsigned short)(uu.x >> 16))     * nhat[jj*8+1]
       + bf2f((unsigned short)(uu.y & 0xffffu)) * nhat[jj*8+2]
       + bf2f((unsigned short)(uu.y >> 16))     * nhat[jj*8+3]
       + bf2f((unsigned short)(uu.z & 0xffffu)) * nhat[jj*8+4]
       + bf2f((unsigned short)(uu.z >> 16))     * nhat[jj*8+5]
       + bf2f((unsigned short)(uu.w & 0xffffu)) * nhat[jj*8+6]
       + bf2f((unsigned short)(uu.w >> 16))     * nhat[jj*8+7];
  }
  l_all[b * L_ + l] = s + biasg[b * L_ + l];
}

// ---------------------------------------------------------------------------
// K7: final softmax per batch — verbatim R20.
// ---------------------------------------------------------------------------
__global__ __launch_bounds__(256) void k_soft2(
    const float* __restrict__ l_all, float* __restrict__ out)
{
  __shared__ float l_lds[2048];
  __shared__ float red[256];
  int b = blockIdx.x, tid = threadIdx.x, lane = tid & 63, wave = tid >> 6;
  for (int i = tid; i < 2048; i += 256) l_lds[i] = l_all[b * L_ + i];
  __syncthreads();
  float mx = -1e30f;
  for (int i = tid; i < 2048; i += 256) mx = fmaxf(mx, l_lds[i]);
  #pragma unroll
  for (int msk = 1; msk < 64; msk <<= 1) mx = fmaxf(mx, __shfl_xor(mx, msk));
  __syncthreads();
  if (lane == 0) red[wave] = mx;
  __syncthreads();
  mx = fmaxf(fmaxf(red[0], red[1]), fmaxf(red[2], red[3]));
  float sm = 0.f;
  for (int i = tid; i < 2048; i += 256) sm += __expf(l_lds[i] - mx);
  #pragma unroll
  for (int msk = 1; msk < 64; msk <<= 1) sm += __shfl_xor(sm, msk);
  __syncthreads();
  if (lane == 0) red[wave] = sm;
  __syncthreads();
  sm = red[0] + red[1] + red[2] + red[3];
  float inv = 1.f / sm;
  for (int i = tid; i < 2048; i += 256) out[b * L_ + i] = __expf(l_lds[i] - mx) * inv;
}

// ---------------------------------------------------------------------------
extern "C" void kernel_launch(void* const* d_in, const int* in_sizes, int n_in,
                              void* d_out, int out_size, void* d_ws, size_t ws_size,
                              hipStream_t stream) {
  const int*   code = (const int*)d_in[0];
  const float* E    = (const float*)d_in[1];
  const float* bt   = (const float*)d_in[2];
  const float* Wx   = (const float*)d_in[3];
  const float* Wh   = (const float*)d_in[4];
  const float* bg   = (const float*)d_in[5];
  const float* c1w  = (const float*)d_in[6];
  const float* c1b  = (const float*)d_in[7];
  const float* c2w  = (const float*)d_in[8];
  const float* c2b  = (const float*)d_in[9];
  const float* c3w  = (const float*)d_in[10];
  const float* c3b  = (const float*)d_in[11];
  char* ws = (char*)d_ws;
  unsigned short* tokpad = (unsigned short*)(ws);               // 33,685,504 B
  unsigned short* xg     = (unsigned short*)(ws + 33685504);    // 67,108,864 B
  unsigned short* c2o    = (unsigned short*)(ws + 100794368);   // 16,777,216 B
  unsigned short* WxT    = (unsigned short*)(ws + 117571584);   //     49,152 B
  unsigned short* c1wT   = (unsigned short*)(ws + 117620736);   //    131,072 B
  unsigned short* c2wT   = (unsigned short*)(ws + 117751808);   //     65,536 B
  float*          htp    = (float*)(ws + 117817344);            //     16,384 B
  float*          biasg  = (float*)(ws + 117833728);            //    524,288 B
  // tail buffers reuse xg space (dead after k_fused):
  float*          alog   = (float*)(ws + 33685504);             //    524,288 B
  float*          npart  = (float*)(ws + 33685504 + 1048576);   //    262,144 B
  float*          l_all  = (float*)(ws + 33685504 + 2097152);   //    524,288 B
  // total ws use: 118,358,016 B

  k_prep  <<<1024, 256, 0, stream>>>(code, bt, Wx, c1w, c2w, tokpad, WxT, c1wT, c2wT, biasg);
  k_xproj <<<1024, 256, 0, stream>>>(code, E, WxT, bg, tokpad, xg);
  k_fused <<<256, 192, 0, stream>>>(xg, Wh, bg, htp, tokpad, c1wT, c1b, c2wT, c2b, c2o);
  k_alpha <<<2048, 256, 0, stream>>>(c2o, htp, c3w, c3b, alog);
  k_soft1 <<<64, 256, 0, stream>>>(alog);
  k_nhat  <<<512, 256, 0, stream>>>(tokpad, alog, npart);
  k_logits<<<512, 256, 0, stream>>>(tokpad, npart, biasg, l_all);
  k_soft2 <<<64, 256, 0, stream>>>(l_all, (float*)d_out);
}